// Round 2
// baseline (1036.020 us; speedup 1.0000x reference)
//
#include <hip/hip_runtime.h>

#define N_VEC 131072   // B*H*W = 32*64*64
#define DIM   64
#define KCODE 1024
#define HW    4096     // H*W
#define DHW   262144   // D*H*W
#define EPS   3.0e-2f  // near-tie margin: ~60x worst-case fp32 score error
#define WLCAP 8192     // worklist capacity (ints)

// ws layout (4-byte units):
//   [0]            loss accumulator (float)
//   [1]            flagged-vector counter (int)
//   [16..16+1024)  code norms (float)
//   [2048..2048+WLCAP) worklist (int)

__global__ void vq_norms(const float* __restrict__ cb, float* __restrict__ norms) {
    int k = blockIdx.x * blockDim.x + threadIdx.x;
    if (k < KCODE) {
        const float4* c = (const float4*)(cb + k * DIM);
        float s = 0.f;
        #pragma unroll
        for (int i = 0; i < DIM / 4; ++i) {
            float4 v = c[i];
            s = fmaf(v.x, v.x, s);
            s = fmaf(v.y, v.y, s);
            s = fmaf(v.z, v.z, s);
            s = fmaf(v.w, v.w, s);
        }
        norms[k] = s;
    }
}

__global__ __launch_bounds__(256) void vq_main(
    const float* __restrict__ z, const float* __restrict__ cb,
    const float* __restrict__ norms, float* __restrict__ out,
    float* __restrict__ loss_acc, int* __restrict__ counter,
    int* __restrict__ worklist, int cap)
{
    const int n  = blockIdx.x * 256 + threadIdx.x;
    const int b  = n >> 12;
    const int hw = n & 4095;

    const float* zp = z + b * DHW + hw;
    float zr[DIM];
    #pragma unroll
    for (int d = 0; d < DIM; ++d) zr[d] = zp[d * HW];

    float znorm = 0.f;
    #pragma unroll
    for (int d = 0; d < DIM; ++d) znorm = fmaf(zr[d], zr[d], znorm);

    float best  = 3.4e38f, best2 = 3.4e38f;
    int   bestk = 0;
    for (int k = 0; k < KCODE; ++k) {
        const float* c = cb + k * DIM;   // wave-uniform address -> scalar-load path
        float a0 = 0.f, a1 = 0.f, a2 = 0.f, a3 = 0.f;
        #pragma unroll
        for (int d = 0; d < DIM; d += 4) {
            a0 = fmaf(zr[d + 0], c[d + 0], a0);
            a1 = fmaf(zr[d + 1], c[d + 1], a1);
            a2 = fmaf(zr[d + 2], c[d + 2], a2);
            a3 = fmaf(zr[d + 3], c[d + 3], a3);
        }
        float dot   = (a0 + a1) + (a2 + a3);
        float score = fmaf(-2.f, dot, norms[k]);
        if (score < best) { best2 = best; best = score; bestk = k; }
        else if (score < best2) { best2 = score; }
    }

    // Near-tie detection: flag for f64 rescue pass
    bool flagged = (best2 - best) < EPS;
    if (flagged) {
        int slot = atomicAdd(counter, 1);
        if (slot < cap) worklist[slot] = n;
        else flagged = false;   // overflow fallback: keep fp32 answer
    }

    float l = 0.f;
    if (!flagged) {
        const float4* c4 = (const float4*)(cb + bestk * DIM);
        float* op = out + b * DHW + hw;
        #pragma unroll
        for (int i = 0; i < DIM / 4; ++i) {
            float4 v = c4[i];
            op[(4 * i + 0) * HW] = v.x;
            op[(4 * i + 1) * HW] = v.y;
            op[(4 * i + 2) * HW] = v.z;
            op[(4 * i + 3) * HW] = v.w;
        }
        l = best + znorm;   // ||z - e_best||^2
    }

    #pragma unroll
    for (int off = 32; off > 0; off >>= 1) l += __shfl_down(l, off, 64);
    __shared__ float wsum[4];
    const int lane = threadIdx.x & 63;
    const int wid  = threadIdx.x >> 6;
    if (lane == 0) wsum[wid] = l;
    __syncthreads();
    if (threadIdx.x == 0) {
        atomicAdd(loss_acc, (wsum[0] + wsum[1]) + (wsum[2] + wsum[3]));
    }
}

// One block per flagged vector: exact f64 rescan of all 1024 codes.
__global__ __launch_bounds__(256) void vq_rescue(
    const float* __restrict__ z, const float* __restrict__ cb,
    float* __restrict__ out, float* __restrict__ loss_acc,
    const int* __restrict__ counter, const int* __restrict__ worklist, int cap)
{
    __shared__ float  zs[DIM];
    __shared__ double vals[256];
    __shared__ int    idxs[256];

    int count = *counter;
    if (count > cap) count = cap;

    for (int i = blockIdx.x; i < count; i += gridDim.x) {
        const int n  = worklist[i];
        const int b  = n >> 12;
        const int hw = n & 4095;
        const float* zp = z + b * DHW + hw;
        if (threadIdx.x < DIM) zs[threadIdx.x] = zp[threadIdx.x * HW];
        __syncthreads();

        double bestd = 1e300;
        int    bestk = 0;
        #pragma unroll
        for (int j = 0; j < 4; ++j) {
            const int k = threadIdx.x * 4 + j;
            const float* c = cb + k * DIM;
            double s = 0.0;
            for (int d = 0; d < DIM; ++d) {
                double diff = (double)zs[d] - (double)c[d];
                s = fma(diff, diff, s);
            }
            if (s < bestd) { bestd = s; bestk = k; }
        }
        vals[threadIdx.x] = bestd;
        idxs[threadIdx.x] = bestk;
        __syncthreads();

        for (int off = 128; off > 0; off >>= 1) {
            if (threadIdx.x < off) {
                double ov = vals[threadIdx.x + off];
                int    oi = idxs[threadIdx.x + off];
                if (ov < vals[threadIdx.x] ||
                    (ov == vals[threadIdx.x] && oi < idxs[threadIdx.x])) {
                    vals[threadIdx.x] = ov;
                    idxs[threadIdx.x] = oi;
                }
            }
            __syncthreads();
        }

        const int    kb    = idxs[0];
        const double resid = vals[0];
        float* op = out + b * DHW + hw;
        if (threadIdx.x < DIM) op[threadIdx.x * HW] = cb[kb * DIM + threadIdx.x];
        if (threadIdx.x == 0) atomicAdd(loss_acc, (float)resid);
        __syncthreads();   // protect zs before next iteration
    }
}

__global__ void vq_finalize(const float* __restrict__ loss_acc,
                            float* __restrict__ loss_out) {
    *loss_out = 1.25f * (*loss_acc) * (1.0f / (float)(N_VEC * DIM));
}

extern "C" void kernel_launch(void* const* d_in, const int* in_sizes, int n_in,
                              void* d_out, int out_size, void* d_ws, size_t ws_size,
                              hipStream_t stream) {
    const float* z  = (const float*)d_in[0];
    const float* cb = (const float*)d_in[1];
    float* out      = (float*)d_out;
    float* ws       = (float*)d_ws;
    float* loss_acc = ws;
    int*   counter  = (int*)(ws + 1);
    float* norms    = ws + 16;
    int*   worklist = (int*)(ws + 2048);

    int cap = WLCAP;
    long avail = (long)(ws_size / 4) - 2048;
    if (avail < cap) cap = (avail > 0) ? (int)avail : 0;

    hipMemsetAsync(d_ws, 0, 64, stream);   // zero loss accumulator + counter
    vq_norms<<<dim3(KCODE / 256), dim3(256), 0, stream>>>(cb, norms);
    vq_main<<<dim3(N_VEC / 256), dim3(256), 0, stream>>>(
        z, cb, norms, out, loss_acc, counter, worklist, cap);
    vq_rescue<<<dim3(512), dim3(256), 0, stream>>>(
        z, cb, out, loss_acc, counter, worklist, cap);
    vq_finalize<<<dim3(1), dim3(1), 0, stream>>>(loss_acc, out + (out_size - 1));
}

// Round 3
// 701.137 us; speedup vs baseline: 1.4776x; 1.4776x over previous
//
#include <hip/hip_runtime.h>

#define N_VEC 131072   // B*H*W = 32*64*64
#define DIM   64
#define KCODE 1024
#define HW    4096     // H*W
#define DHW   262144   // D*H*W
#define EPS   3.0e-2f  // near-tie margin: ~60x worst-case fp32 score error
#define WLCAP 8192     // worklist capacity (ints)

// ws layout (bytes):
//   [0..8)        double loss accumulator
//   [8..12)       int flagged-vector counter
//   [64..4160)    code norms (1024 floats)
//   [8192..)      worklist (ints)

__global__ void vq_norms(const float* __restrict__ cb, float* __restrict__ norms) {
    int k = blockIdx.x * blockDim.x + threadIdx.x;
    if (k < KCODE) {
        const float4* c = (const float4*)(cb + k * DIM);
        float s = 0.f;
        #pragma unroll
        for (int i = 0; i < DIM / 4; ++i) {
            float4 v = c[i];
            s = fmaf(v.x, v.x, s);
            s = fmaf(v.y, v.y, s);
            s = fmaf(v.z, v.z, s);
            s = fmaf(v.w, v.w, s);
        }
        norms[k] = s;
    }
}

__global__ __launch_bounds__(256, 2) void vq_main(
    const float* __restrict__ z, const float* __restrict__ cb,
    const float* __restrict__ norms, float* __restrict__ out,
    double* __restrict__ loss_acc, int* __restrict__ counter,
    int* __restrict__ worklist, int cap)
{
    const int n  = blockIdx.x * 256 + threadIdx.x;
    const int b  = n >> 12;
    const int hw = n & 4095;

    const float* zp = z + b * DHW + hw;
    float zr[DIM];
    #pragma unroll
    for (int d = 0; d < DIM; ++d) zr[d] = zp[d * HW];

    float znorm = 0.f;
    #pragma unroll
    for (int d = 0; d < DIM; ++d) znorm = fmaf(zr[d], zr[d], znorm);

    float best  = 3.4e38f, best2 = 3.4e38f;
    int   bestk = 0;
    // 2 codes per iteration: scalar loads for both pipeline behind FMAs,
    // independent accumulator sets give the scheduler ILP.
    for (int k = 0; k < KCODE; k += 2) {
        const float4* cA = (const float4*)(cb + k * DIM);         // wave-uniform
        const float4* cB = (const float4*)(cb + k * DIM + DIM);   // wave-uniform
        float a0 = 0.f, a1 = 0.f, a2 = 0.f, a3 = 0.f;
        float b0 = 0.f, b1 = 0.f, b2 = 0.f, b3 = 0.f;
        #pragma unroll
        for (int i = 0; i < DIM / 4; ++i) {
            float4 va = cA[i];
            float4 vb = cB[i];
            a0 = fmaf(zr[4 * i + 0], va.x, a0);
            a1 = fmaf(zr[4 * i + 1], va.y, a1);
            a2 = fmaf(zr[4 * i + 2], va.z, a2);
            a3 = fmaf(zr[4 * i + 3], va.w, a3);
            b0 = fmaf(zr[4 * i + 0], vb.x, b0);
            b1 = fmaf(zr[4 * i + 1], vb.y, b1);
            b2 = fmaf(zr[4 * i + 2], vb.z, b2);
            b3 = fmaf(zr[4 * i + 3], vb.w, b3);
        }
        float dotA   = (a0 + a1) + (a2 + a3);
        float scoreA = fmaf(-2.f, dotA, norms[k]);
        if (scoreA < best) { best2 = best; best = scoreA; bestk = k; }
        else if (scoreA < best2) { best2 = scoreA; }
        float dotB   = (b0 + b1) + (b2 + b3);
        float scoreB = fmaf(-2.f, dotB, norms[k + 1]);
        if (scoreB < best) { best2 = best; best = scoreB; bestk = k + 1; }
        else if (scoreB < best2) { best2 = scoreB; }
    }

    // Near-tie detection: flag for f64 rescue pass
    bool flagged = (best2 - best) < EPS;
    if (flagged) {
        int slot = atomicAdd(counter, 1);
        if (slot < cap) worklist[slot] = n;
        else flagged = false;   // overflow fallback: keep fp32 answer
    }

    float l = 0.f;
    if (!flagged) {
        const float4* c4 = (const float4*)(cb + bestk * DIM);
        float* op = out + b * DHW + hw;
        #pragma unroll
        for (int i = 0; i < DIM / 4; ++i) {
            float4 v = c4[i];
            op[(4 * i + 0) * HW] = v.x;
            op[(4 * i + 1) * HW] = v.y;
            op[(4 * i + 2) * HW] = v.z;
            op[(4 * i + 3) * HW] = v.w;
        }
        l = best + znorm;   // ||z - e_best||^2
    }

    #pragma unroll
    for (int off = 32; off > 0; off >>= 1) l += __shfl_down(l, off, 64);
    __shared__ float wsum[4];
    const int lane = threadIdx.x & 63;
    const int wid  = threadIdx.x >> 6;
    if (lane == 0) wsum[wid] = l;
    __syncthreads();
    if (threadIdx.x == 0) {
        double blk = ((double)wsum[0] + (double)wsum[1]) +
                     ((double)wsum[2] + (double)wsum[3]);
        atomicAdd(loss_acc, blk);
    }
}

// One block per flagged vector: exact f64 rescan of all 1024 codes.
__global__ __launch_bounds__(256) void vq_rescue(
    const float* __restrict__ z, const float* __restrict__ cb,
    float* __restrict__ out, double* __restrict__ loss_acc,
    const int* __restrict__ counter, const int* __restrict__ worklist, int cap)
{
    __shared__ float  zs[DIM];
    __shared__ double vals[256];
    __shared__ int    idxs[256];

    int count = *counter;
    if (count > cap) count = cap;

    for (int i = blockIdx.x; i < count; i += gridDim.x) {
        const int n  = worklist[i];
        const int b  = n >> 12;
        const int hw = n & 4095;
        const float* zp = z + b * DHW + hw;
        if (threadIdx.x < DIM) zs[threadIdx.x] = zp[threadIdx.x * HW];
        __syncthreads();

        double bestd = 1e300;
        int    bestk = 0;
        #pragma unroll
        for (int j = 0; j < 4; ++j) {
            const int k = threadIdx.x * 4 + j;
            const float* c = cb + k * DIM;
            double s = 0.0;
            for (int d = 0; d < DIM; ++d) {
                double diff = (double)zs[d] - (double)c[d];
                s = fma(diff, diff, s);
            }
            if (s < bestd) { bestd = s; bestk = k; }
        }
        vals[threadIdx.x] = bestd;
        idxs[threadIdx.x] = bestk;
        __syncthreads();

        for (int off = 128; off > 0; off >>= 1) {
            if (threadIdx.x < off) {
                double ov = vals[threadIdx.x + off];
                int    oi = idxs[threadIdx.x + off];
                if (ov < vals[threadIdx.x] ||
                    (ov == vals[threadIdx.x] && oi < idxs[threadIdx.x])) {
                    vals[threadIdx.x] = ov;
                    idxs[threadIdx.x] = oi;
                }
            }
            __syncthreads();
        }

        const int    kb    = idxs[0];
        const double resid = vals[0];
        float* op = out + b * DHW + hw;
        if (threadIdx.x < DIM) op[threadIdx.x * HW] = cb[kb * DIM + threadIdx.x];
        if (threadIdx.x == 0) atomicAdd(loss_acc, resid);
        __syncthreads();   // protect zs before next iteration
    }
}

__global__ void vq_finalize(const double* __restrict__ loss_acc,
                            float* __restrict__ loss_out) {
    *loss_out = (float)(1.25 * (*loss_acc) * (1.0 / (double)((long)N_VEC * DIM)));
}

extern "C" void kernel_launch(void* const* d_in, const int* in_sizes, int n_in,
                              void* d_out, int out_size, void* d_ws, size_t ws_size,
                              hipStream_t stream) {
    const float* z  = (const float*)d_in[0];
    const float* cb = (const float*)d_in[1];
    float* out      = (float*)d_out;
    char*  ws       = (char*)d_ws;
    double* loss_acc = (double*)ws;
    int*    counter  = (int*)(ws + 8);
    float*  norms    = (float*)(ws + 64);
    int*    worklist = (int*)(ws + 8192);

    int cap = WLCAP;
    long avail = ((long)ws_size - 8192) / 4;
    if (avail < cap) cap = (avail > 0) ? (int)avail : 0;

    hipMemsetAsync(d_ws, 0, 64, stream);   // zero loss accumulator + counter
    vq_norms<<<dim3(KCODE / 256), dim3(256), 0, stream>>>(cb, norms);
    vq_main<<<dim3(N_VEC / 256), dim3(256), 0, stream>>>(
        z, cb, norms, out, loss_acc, counter, worklist, cap);
    vq_rescue<<<dim3(512), dim3(256), 0, stream>>>(
        z, cb, out, loss_acc, counter, worklist, cap);
    vq_finalize<<<dim3(1), dim3(1), 0, stream>>>(loss_acc, out + (out_size - 1));
}

// Round 4
// 391.014 us; speedup vs baseline: 2.6496x; 1.7931x over previous
//
#include <hip/hip_runtime.h>

#define N_VEC 131072   // B*H*W
#define DIM   64
#define KCODE 1024
#define HW    4096
#define DHW   262144
#define EPS   0.25f    // near-tie margin (covers packing 2^-5 + bf16x3 error, 1.7x slack)
#define WLCAP 32768
#define BLK_ROWS 128
#define PITCH 72       // shorts per LDS row: 64 + 8 pad (144 B, 16B-aligned, conflict-light)
#define RV 16          // vectors per rescue block

typedef short short8 __attribute__((ext_vector_type(8)));
typedef float f32x4  __attribute__((ext_vector_type(4)));

// ws layout (bytes):
//   0      : double loss accumulator
//   8      : int flagged counter
//   64     : norms f32[1024]
//   8192   : eh  bf16-bits short[65536]   (hi part of codebook)
//   139264 : el  bf16-bits short[65536]   (lo part)
//   270336 : worklist int[WLCAP]

__device__ __forceinline__ unsigned short f32_to_bf16_rne(float x) {
    unsigned u = __float_as_uint(x);
    u += 0x7FFFu + ((u >> 16) & 1u);
    return (unsigned short)(u >> 16);
}
__device__ __forceinline__ float bf16_to_f32(unsigned short h) {
    return __uint_as_float((unsigned)h << 16);
}

__global__ void vq_prep(const float* __restrict__ cb, float* __restrict__ norms,
                        short* __restrict__ ehg, short* __restrict__ elg) {
    int k = blockIdx.x * 256 + threadIdx.x;
    if (k < KCODE) {
        float s = 0.f;
        for (int d = 0; d < DIM; ++d) {
            float v = cb[k * DIM + d];
            s = fmaf(v, v, s);
            unsigned short h = f32_to_bf16_rne(v);
            unsigned short l = f32_to_bf16_rne(v - bf16_to_f32(h));
            ehg[k * DIM + d] = (short)h;
            elg[k * DIM + d] = (short)l;
        }
        norms[k] = s;
    }
}

__global__ __launch_bounds__(256, 4) void vq_main(
    const float* __restrict__ z, const float* __restrict__ cb,
    const float* __restrict__ norms, const short* __restrict__ ehg,
    const short* __restrict__ elg, float* __restrict__ out,
    double* __restrict__ loss_acc, int* __restrict__ counter,
    int* __restrict__ worklist, int cap)
{
    __shared__ short zh[BLK_ROWS * PITCH];   // bf16 bits of hi(-2z), [row][d]
    __shared__ short zl[BLK_ROWS * PITCH];   // bf16 bits of lo(-2z)
    __shared__ int   kidx[BLK_ROWS];
    __shared__ float wsum[4];

    const int t   = threadIdx.x;
    const int n0  = blockIdx.x * BLK_ROWS;
    const int b   = n0 >> 12;
    const int hw0 = n0 & 4095;

    // ---- stage (-2z) -> LDS as bf16 hi/lo, layout [row=hw][d] ----
    {
        const int hwl = t & 127;
        const int dp  = t >> 7;            // 0..1
        for (int s = 0; s < 16; ++s) {
            const int d0 = s * 4 + dp * 2;
            float v0 = -2.0f * z[(size_t)b * DHW + (size_t)d0 * HW + hw0 + hwl];
            float v1 = -2.0f * z[(size_t)b * DHW + (size_t)(d0 + 1) * HW + hw0 + hwl];
            unsigned short h0 = f32_to_bf16_rne(v0);
            unsigned short h1 = f32_to_bf16_rne(v1);
            unsigned short l0 = f32_to_bf16_rne(v0 - bf16_to_f32(h0));
            unsigned short l1 = f32_to_bf16_rne(v1 - bf16_to_f32(h1));
            int si = hwl * PITCH + d0;     // even -> int-aligned
            ((int*)zh)[si >> 1] = ((int)h1 << 16) | h0;
            ((int*)zl)[si >> 1] = ((int)l1 << 16) | l0;
        }
    }
    __syncthreads();

    const int lane = t & 63;
    const int wave = t >> 6;
    const int l15  = lane & 15;
    const int quad = lane >> 4;
    const int rowbase = wave * 32;         // each wave owns 32 rows (2 row-tiles)

    // ---- A-fragments from LDS (held in registers for the whole scan) ----
    short8 a_h[2][2], a_l[2][2];
    #pragma unroll
    for (int rt = 0; rt < 2; ++rt)
        #pragma unroll
        for (int kt = 0; kt < 2; ++kt) {
            int idx = (rowbase + rt * 16 + l15) * PITCH + kt * 32 + quad * 8;
            a_h[rt][kt] = *(const short8*)&zh[idx];
            a_l[rt][kt] = *(const short8*)&zl[idx];
        }

    // ---- scan 64 code-tiles of 16 codes ----
    float best[2][4], best2[2][4];
    #pragma unroll
    for (int rt = 0; rt < 2; ++rt)
        #pragma unroll
        for (int r = 0; r < 4; ++r) { best[rt][r] = 3.0e38f; best2[rt][r] = 3.0e38f; }

    for (int tile = 0; tile < 64; ++tile) {
        const int code = tile * 16 + l15;
        const short* bh = ehg + code * DIM + quad * 8;
        const short* bl = elg + code * DIM + quad * 8;
        short8 b_h0 = *(const short8*)(bh);
        short8 b_h1 = *(const short8*)(bh + 32);
        short8 b_l0 = *(const short8*)(bl);
        short8 b_l1 = *(const short8*)(bl + 32);
        float nrm = norms[code];
        unsigned colbits = (unsigned)code;

        #pragma unroll
        for (int rt = 0; rt < 2; ++rt) {
            f32x4 acc = { nrm, nrm, nrm, nrm };
            acc = __builtin_amdgcn_mfma_f32_16x16x32_bf16(a_h[rt][0], b_h0, acc, 0, 0, 0);
            acc = __builtin_amdgcn_mfma_f32_16x16x32_bf16(a_h[rt][1], b_h1, acc, 0, 0, 0);
            acc = __builtin_amdgcn_mfma_f32_16x16x32_bf16(a_h[rt][0], b_l0, acc, 0, 0, 0);
            acc = __builtin_amdgcn_mfma_f32_16x16x32_bf16(a_h[rt][1], b_l1, acc, 0, 0, 0);
            acc = __builtin_amdgcn_mfma_f32_16x16x32_bf16(a_l[rt][0], b_h0, acc, 0, 0, 0);
            acc = __builtin_amdgcn_mfma_f32_16x16x32_bf16(a_l[rt][1], b_h1, acc, 0, 0, 0);
            #pragma unroll
            for (int r = 0; r < 4; ++r) {
                float p = __uint_as_float((__float_as_uint(acc[r]) & 0xFFFFFC00u) | colbits);
                best2[rt][r] = fminf(best2[rt][r], fmaxf(best[rt][r], p));
                best[rt][r]  = fminf(best[rt][r], p);
            }
        }
    }

    // ---- cross-lane reduce (cols live in 16-lane groups) ----
    #pragma unroll
    for (int rt = 0; rt < 2; ++rt)
        #pragma unroll
        for (int r = 0; r < 4; ++r) {
            float bb = best[rt][r], b2 = best2[rt][r];
            #pragma unroll
            for (int m = 1; m <= 8; m <<= 1) {
                float ob  = __shfl_xor(bb, m, 64);
                float ob2 = __shfl_xor(b2, m, 64);
                b2 = fminf(fminf(b2, ob2), fmaxf(bb, ob));
                bb = fminf(bb, ob);
            }
            best[rt][r] = bb; best2[rt][r] = b2;
        }

    // ---- per-row result: index, flag, worklist ----
    if (l15 == 0) {
        #pragma unroll
        for (int rt = 0; rt < 2; ++rt)
            #pragma unroll
            for (int r = 0; r < 4; ++r) {
                unsigned ub = __float_as_uint(best[rt][r]);
                int k = (int)(ub & 1023u);
                float sb  = __uint_as_float(ub & 0xFFFFFC00u);
                float sb2 = __uint_as_float(__float_as_uint(best2[rt][r]) & 0xFFFFFC00u);
                int rowl = rt * 16 + quad * 4 + r;    // within this wave's 32 rows
                int flag = 0;
                if (sb2 - sb < EPS) {
                    int slot = atomicAdd(counter, 1);
                    if (slot < cap) { worklist[slot] = n0 + rowbase + rowl; flag = 1; }
                }
                kidx[rowbase + rowl] = k | (flag << 15);
            }
    }
    __syncthreads();

    // ---- output write + exact fp32 loss (skip flagged rows: rescue owns them) ----
    float lsum = 0.f;
    {
        const int row32 = lane & 31;
        const int dhalf = lane >> 5;
        const int rowl  = rowbase + row32;
        const int ki    = kidx[rowl];
        const int k     = ki & 1023;
        const int flag  = (ki >> 15) & 1;
        const float* cbr = cb + k * DIM;
        float* op = out + (size_t)b * DHW + hw0 + rowl;
        const int lb = rowl * PITCH;
        if (!flag) {
            for (int i = 0; i < 32; ++i) {
                int d = i * 2 + dhalf;
                float e  = cbr[d];
                float zv = -0.5f * (bf16_to_f32((unsigned short)zh[lb + d]) +
                                    bf16_to_f32((unsigned short)zl[lb + d]));
                op[(size_t)d * HW] = e;
                float df = e - zv;
                lsum = fmaf(df, df, lsum);
            }
        }
    }
    #pragma unroll
    for (int off = 32; off > 0; off >>= 1) lsum += __shfl_down(lsum, off, 64);
    if (lane == 0) wsum[wave] = lsum;
    __syncthreads();
    if (t == 0)
        atomicAdd(loss_acc, (double)((wsum[0] + wsum[1]) + (wsum[2] + wsum[3])));
}

// Exact f64 rescan for flagged vectors; RV vectors per block, codebook LDS-chunked.
__global__ __launch_bounds__(256) void vq_rescue(
    const float* __restrict__ z, const float* __restrict__ cb,
    float* __restrict__ out, double* __restrict__ loss_acc,
    const int* __restrict__ counter, const int* __restrict__ worklist, int cap)
{
    __shared__ float  cbs[128 * DIM];   // 32 KB codebook chunk
    __shared__ float  zsv[RV * DIM];
    __shared__ double rvals[256];
    __shared__ int    ridx[256];
    __shared__ int    rn[RV];

    int count = *counter; if (count > cap) count = cap;
    const int base = blockIdx.x * RV;
    if (base >= count) return;
    int nv = count - base; if (nv > RV) nv = RV;

    const int t   = threadIdx.x;
    const int v   = t & 15;
    const int sub = t >> 4;

    if (t < nv) rn[t] = worklist[base + t];
    __syncthreads();
    if (v < nv) {
        const int n = rn[v];
        const int b = n >> 12, hw = n & 4095;
        #pragma unroll
        for (int j = 0; j < 4; ++j) {
            int d = sub * 4 + j;
            zsv[v * DIM + d] = z[(size_t)b * DHW + (size_t)d * HW + hw];
        }
    }
    __syncthreads();

    double bestd = 1e300; int bestk = 0;
    for (int chunk = 0; chunk < 8; ++chunk) {
        const float4* src = (const float4*)(cb + chunk * 128 * DIM);
        float4* dst = (float4*)cbs;
        for (int i = t; i < 128 * DIM / 4; i += 256) dst[i] = src[i];
        __syncthreads();
        if (v < nv) {
            for (int j = 0; j < 8; ++j) {
                const int c = sub * 8 + j;
                const float* cr = cbs + c * DIM;
                const float* zr = zsv + v * DIM;
                double s = 0.0;
                for (int d = 0; d < DIM; ++d) {
                    double diff = (double)zr[d] - (double)cr[d];
                    s = fma(diff, diff, s);
                }
                const int gk = chunk * 128 + c;
                if (s < bestd) { bestd = s; bestk = gk; }
            }
        }
        __syncthreads();
    }
    rvals[t] = bestd; ridx[t] = bestk;
    __syncthreads();
    for (int s = 8; s > 0; s >>= 1) {
        if (sub < s) {
            double ov = rvals[t + 16 * s]; int oi = ridx[t + 16 * s];
            if (ov < rvals[t] || (ov == rvals[t] && oi < ridx[t])) {
                rvals[t] = ov; ridx[t] = oi;
            }
        }
        __syncthreads();
    }
    if (v < nv) {
        const int n = rn[v];
        const int b = n >> 12, hw = n & 4095;
        const int kb = ridx[v];
        #pragma unroll
        for (int j = 0; j < 4; ++j) {
            int d = sub * 4 + j;
            out[(size_t)b * DHW + (size_t)d * HW + hw] = cb[kb * DIM + d];
        }
        if (sub == 0) atomicAdd(loss_acc, rvals[v]);
    }
}

__global__ void vq_finalize(const double* __restrict__ loss_acc,
                            float* __restrict__ loss_out) {
    *loss_out = (float)(1.25 * (*loss_acc) * (1.0 / (double)((long)N_VEC * DIM)));
}

extern "C" void kernel_launch(void* const* d_in, const int* in_sizes, int n_in,
                              void* d_out, int out_size, void* d_ws, size_t ws_size,
                              hipStream_t stream) {
    const float* z  = (const float*)d_in[0];
    const float* cb = (const float*)d_in[1];
    float* out      = (float*)d_out;
    char*  ws       = (char*)d_ws;

    double* loss_acc = (double*)ws;
    int*    counter  = (int*)(ws + 8);
    float*  norms    = (float*)(ws + 64);
    short*  ehg      = (short*)(ws + 8192);
    short*  elg      = (short*)(ws + 139264);
    int*    worklist = (int*)(ws + 270336);

    int cap = WLCAP;
    long avail = ((long)ws_size - 270336) / 4;
    if (avail < cap) cap = (avail > 0) ? (int)avail : 0;

    hipMemsetAsync(d_ws, 0, 16, stream);
    vq_prep<<<dim3(KCODE / 256), dim3(256), 0, stream>>>(cb, norms, ehg, elg);
    vq_main<<<dim3(N_VEC / BLK_ROWS), dim3(256), 0, stream>>>(
        z, cb, norms, ehg, elg, out, loss_acc, counter, worklist, cap);
    vq_rescue<<<dim3(WLCAP / RV), dim3(256), 0, stream>>>(
        z, cb, out, loss_acc, counter, worklist, cap);
    vq_finalize<<<dim3(1), dim3(1), 0, stream>>>(loss_acc, out + (out_size - 1));
}

// Round 5
// 352.089 us; speedup vs baseline: 2.9425x; 1.1106x over previous
//
#include <hip/hip_runtime.h>

#define N_VEC 131072   // B*H*W
#define DIM   64
#define KCODE 1024
#define HW    4096
#define DHW   262144
#define EPS   0.25f    // near-tie margin (covers packing 2^-5 + bf16x3 error)
#define WLCAP 32768
#define BLK_ROWS 128
#define PITCH 72       // shorts per LDS row (144 B: keeps b128 16B-aligned)
#define RV 16          // vectors per rescue block

typedef short short8 __attribute__((ext_vector_type(8)));
typedef float f32x4  __attribute__((ext_vector_type(4)));

// ws layout (bytes):
//   0      : double loss accumulator
//   8      : int flagged counter
//   64     : norms f32[1024]
//   8192   : eh  bf16-bits short[65536]
//   139264 : el  bf16-bits short[65536]
//   270336 : worklist int[WLCAP]

__device__ __forceinline__ unsigned short f32_to_bf16_rne(float x) {
    unsigned u = __float_as_uint(x);
    u += 0x7FFFu + ((u >> 16) & 1u);
    return (unsigned short)(u >> 16);
}
__device__ __forceinline__ float bf16_to_f32(unsigned short h) {
    return __uint_as_float((unsigned)h << 16);
}

// 64 blocks x 256 threads: thread = (code k = blk*16 + t>>4, part = t&15 -> 4 d's)
__global__ __launch_bounds__(256) void vq_prep(
    const float* __restrict__ cb, float* __restrict__ norms,
    short* __restrict__ ehg, short* __restrict__ elg)
{
    const int t    = threadIdx.x;
    const int k    = blockIdx.x * 16 + (t >> 4);
    const int part = t & 15;
    const float4 v = *(const float4*)(cb + k * DIM + part * 4);

    float s = 0.f;
    s = fmaf(v.x, v.x, s); s = fmaf(v.y, v.y, s);
    s = fmaf(v.z, v.z, s); s = fmaf(v.w, v.w, s);
    #pragma unroll
    for (int m = 1; m <= 8; m <<= 1) s += __shfl_xor(s, m, 64);
    if (part == 0) norms[k] = s;

    short h[4], l[4];
    const float vv[4] = { v.x, v.y, v.z, v.w };
    #pragma unroll
    for (int j = 0; j < 4; ++j) {
        unsigned short hh = f32_to_bf16_rne(vv[j]);
        unsigned short ll = f32_to_bf16_rne(vv[j] - bf16_to_f32(hh));
        h[j] = (short)hh; l[j] = (short)ll;
    }
    *(short4*)(ehg + k * DIM + part * 4) = make_short4(h[0], h[1], h[2], h[3]);
    *(short4*)(elg + k * DIM + part * 4) = make_short4(l[0], l[1], l[2], l[3]);
}

__global__ __launch_bounds__(256, 3) void vq_main(
    const float* __restrict__ z, const float* __restrict__ cb,
    const float* __restrict__ norms, const short* __restrict__ ehg,
    const short* __restrict__ elg, float* __restrict__ out,
    double* __restrict__ loss_acc, int* __restrict__ counter,
    int* __restrict__ worklist, int cap)
{
    __shared__ short zh[BLK_ROWS * PITCH];   // bf16 bits of hi(-2z), [row=hw][d]
    __shared__ short zl[BLK_ROWS * PITCH];
    __shared__ int   kidx[BLK_ROWS];
    __shared__ float wsum[4];

    const int t   = threadIdx.x;
    const int n0  = blockIdx.x * BLK_ROWS;
    const int b   = n0 >> 12;
    const int hw0 = n0 & 4095;

    // ---- stage: 8 independent float4 loads along hw, register transpose, b128 writes ----
    {
        const int hwl   = (t & 31) * 4;      // 4 consecutive rows (hw)
        const int dbase = (t >> 5) * 8;      // 8 consecutive d
        float4 v[8];
        #pragma unroll
        for (int p = 0; p < 8; ++p)
            v[p] = *(const float4*)(z + (size_t)b * DHW + (size_t)(dbase + p) * HW + hw0 + hwl);
        float  f[8][4];
        #pragma unroll
        for (int p = 0; p < 8; ++p) {
            f[p][0] = -2.0f * v[p].x; f[p][1] = -2.0f * v[p].y;
            f[p][2] = -2.0f * v[p].z; f[p][3] = -2.0f * v[p].w;
        }
        #pragma unroll
        for (int c = 0; c < 4; ++c) {
            short8 hi, lo;
            #pragma unroll
            for (int p = 0; p < 8; ++p) {
                unsigned short hh = f32_to_bf16_rne(f[p][c]);
                unsigned short ll = f32_to_bf16_rne(f[p][c] - bf16_to_f32(hh));
                hi[p] = (short)hh; lo[p] = (short)ll;
            }
            *(short8*)&zh[(hwl + c) * PITCH + dbase] = hi;
            *(short8*)&zl[(hwl + c) * PITCH + dbase] = lo;
        }
    }
    __syncthreads();

    const int lane = t & 63;
    const int wave = t >> 6;
    const int l15  = lane & 15;
    const int quad = lane >> 4;
    const int rowbase = wave * 32;

    // ---- A-fragments (registers for whole scan) ----
    short8 a_h[2][2], a_l[2][2];
    #pragma unroll
    for (int rt = 0; rt < 2; ++rt)
        #pragma unroll
        for (int kt = 0; kt < 2; ++kt) {
            int idx = (rowbase + rt * 16 + l15) * PITCH + kt * 32 + quad * 8;
            a_h[rt][kt] = *(const short8*)&zh[idx];
            a_l[rt][kt] = *(const short8*)&zl[idx];
        }

    float best[2][4], best2[2][4];
    #pragma unroll
    for (int rt = 0; rt < 2; ++rt)
        #pragma unroll
        for (int r = 0; r < 4; ++r) { best[rt][r] = 3.0e38f; best2[rt][r] = 3.0e38f; }

    // ---- scan: 64 tiles, double-buffered B prefetch ----
    const short* bhbase = ehg + l15 * DIM + quad * 8;
    const short* blbase = elg + l15 * DIM + quad * 8;
    const float* nrmp   = norms + l15;

    short8 B[2][4];
    float  NR[2];
    B[0][0] = *(const short8*)(bhbase);
    B[0][1] = *(const short8*)(bhbase + 32);
    B[0][2] = *(const short8*)(blbase);
    B[0][3] = *(const short8*)(blbase + 32);
    NR[0]   = nrmp[0];

#define VQ_COMPUTE(BUF, TILE)                                                        \
    {                                                                                \
        const unsigned colbits = (unsigned)((TILE) * 16 + l15);                      \
        _Pragma("unroll")                                                            \
        for (int rt = 0; rt < 2; ++rt) {                                             \
            f32x4 acc = { NR[BUF], NR[BUF], NR[BUF], NR[BUF] };                      \
            acc = __builtin_amdgcn_mfma_f32_16x16x32_bf16(a_h[rt][0], B[BUF][0], acc, 0, 0, 0); \
            acc = __builtin_amdgcn_mfma_f32_16x16x32_bf16(a_h[rt][1], B[BUF][1], acc, 0, 0, 0); \
            acc = __builtin_amdgcn_mfma_f32_16x16x32_bf16(a_h[rt][0], B[BUF][2], acc, 0, 0, 0); \
            acc = __builtin_amdgcn_mfma_f32_16x16x32_bf16(a_h[rt][1], B[BUF][3], acc, 0, 0, 0); \
            acc = __builtin_amdgcn_mfma_f32_16x16x32_bf16(a_l[rt][0], B[BUF][0], acc, 0, 0, 0); \
            acc = __builtin_amdgcn_mfma_f32_16x16x32_bf16(a_l[rt][1], B[BUF][1], acc, 0, 0, 0); \
            _Pragma("unroll")                                                        \
            for (int r = 0; r < 4; ++r) {                                            \
                float p = __uint_as_float((__float_as_uint(acc[r]) & 0xFFFFFC00u) | colbits); \
                best2[rt][r] = fminf(best2[rt][r], fmaxf(best[rt][r], p));           \
                best[rt][r]  = fminf(best[rt][r], p);                                \
            }                                                                        \
        }                                                                            \
    }

    for (int tile = 0; tile < 64; tile += 2) {
        {   // prefetch tile+1 -> buf 1 (tile+1 <= 63 always)
            const short* p = bhbase + (tile + 1) * 1024;
            const short* q = blbase + (tile + 1) * 1024;
            B[1][0] = *(const short8*)(p);
            B[1][1] = *(const short8*)(p + 32);
            B[1][2] = *(const short8*)(q);
            B[1][3] = *(const short8*)(q + 32);
            NR[1]   = nrmp[(tile + 1) * 16];
        }
        VQ_COMPUTE(0, tile)
        if (tile + 2 < 64) {   // prefetch tile+2 -> buf 0
            const short* p = bhbase + (tile + 2) * 1024;
            const short* q = blbase + (tile + 2) * 1024;
            B[0][0] = *(const short8*)(p);
            B[0][1] = *(const short8*)(p + 32);
            B[0][2] = *(const short8*)(q);
            B[0][3] = *(const short8*)(q + 32);
            NR[0]   = nrmp[(tile + 2) * 16];
        }
        VQ_COMPUTE(1, tile + 1)
    }
#undef VQ_COMPUTE

    // ---- cross-lane top-2 merge (cols live in 16-lane groups) ----
    #pragma unroll
    for (int rt = 0; rt < 2; ++rt)
        #pragma unroll
        for (int r = 0; r < 4; ++r) {
            float bb = best[rt][r], b2 = best2[rt][r];
            #pragma unroll
            for (int m = 1; m <= 8; m <<= 1) {
                float ob  = __shfl_xor(bb, m, 64);
                float ob2 = __shfl_xor(b2, m, 64);
                b2 = fminf(fminf(b2, ob2), fmaxf(bb, ob));
                bb = fminf(bb, ob);
            }
            best[rt][r] = bb; best2[rt][r] = b2;
        }

    // ---- per-row result: index, flag, worklist ----
    if (l15 == 0) {
        #pragma unroll
        for (int rt = 0; rt < 2; ++rt)
            #pragma unroll
            for (int r = 0; r < 4; ++r) {
                unsigned ub = __float_as_uint(best[rt][r]);
                int k = (int)(ub & 1023u);
                float sb  = __uint_as_float(ub & 0xFFFFFC00u);
                float sb2 = __uint_as_float(__float_as_uint(best2[rt][r]) & 0xFFFFFC00u);
                int rowl = rt * 16 + quad * 4 + r;
                int flag = 0;
                if (sb2 - sb < EPS) {
                    int slot = atomicAdd(counter, 1);
                    if (slot < cap) { worklist[slot] = n0 + rowbase + rowl; flag = 1; }
                }
                kidx[rowbase + rowl] = k | (flag << 15);
            }
    }
    __syncthreads();

    // ---- output write + exact fp32 loss (flagged rows -> rescue) ----
    float lsum = 0.f;
    {
        const int row32 = lane & 31;
        const int dhalf = lane >> 5;
        const int rowl  = rowbase + row32;
        const int ki    = kidx[rowl];
        const int k     = ki & 1023;
        const int flag  = (ki >> 15) & 1;
        const float* cbr = cb + k * DIM;
        float* op = out + (size_t)b * DHW + hw0 + rowl;
        const int lb = rowl * PITCH;
        if (!flag) {
            #pragma unroll 8
            for (int i = 0; i < 32; ++i) {
                int d = i * 2 + dhalf;
                float e  = cbr[d];
                float zv = -0.5f * (bf16_to_f32((unsigned short)zh[lb + d]) +
                                    bf16_to_f32((unsigned short)zl[lb + d]));
                op[(size_t)d * HW] = e;
                float df = e - zv;
                lsum = fmaf(df, df, lsum);
            }
        }
    }
    #pragma unroll
    for (int off = 32; off > 0; off >>= 1) lsum += __shfl_down(lsum, off, 64);
    if (lane == 0) wsum[wave] = lsum;
    __syncthreads();
    if (t == 0)
        atomicAdd(loss_acc, (double)((wsum[0] + wsum[1]) + (wsum[2] + wsum[3])));
}

// Exact f64 rescan for flagged vectors; RV per block, codebook LDS-chunked.
__global__ __launch_bounds__(256) void vq_rescue(
    const float* __restrict__ z, const float* __restrict__ cb,
    float* __restrict__ out, double* __restrict__ loss_acc,
    const int* __restrict__ counter, const int* __restrict__ worklist, int cap)
{
    __shared__ float  cbs[128 * DIM];
    __shared__ float  zsv[RV * DIM];
    __shared__ double rvals[256];
    __shared__ int    ridx[256];
    __shared__ int    rn[RV];

    int count = *counter; if (count > cap) count = cap;
    const int base = blockIdx.x * RV;
    if (base >= count) return;
    int nv = count - base; if (nv > RV) nv = RV;

    const int t   = threadIdx.x;
    const int v   = t & 15;
    const int sub = t >> 4;

    if (t < nv) rn[t] = worklist[base + t];
    __syncthreads();
    if (v < nv) {
        const int n = rn[v];
        const int b = n >> 12, hw = n & 4095;
        #pragma unroll
        for (int j = 0; j < 4; ++j) {
            int d = sub * 4 + j;
            zsv[v * DIM + d] = z[(size_t)b * DHW + (size_t)d * HW + hw];
        }
    }
    __syncthreads();

    double bestd = 1e300; int bestk = 0;
    for (int chunk = 0; chunk < 8; ++chunk) {
        const float4* src = (const float4*)(cb + chunk * 128 * DIM);
        float4* dst = (float4*)cbs;
        for (int i = t; i < 128 * DIM / 4; i += 256) dst[i] = src[i];
        __syncthreads();
        if (v < nv) {
            for (int j = 0; j < 8; ++j) {
                const int c = sub * 8 + j;
                const float* cr = cbs + c * DIM;
                const float* zr = zsv + v * DIM;
                double s = 0.0;
                for (int d = 0; d < DIM; ++d) {
                    double diff = (double)zr[d] - (double)cr[d];
                    s = fma(diff, diff, s);
                }
                const int gk = chunk * 128 + c;
                if (s < bestd) { bestd = s; bestk = gk; }
            }
        }
        __syncthreads();
    }
    rvals[t] = bestd; ridx[t] = bestk;
    __syncthreads();
    for (int s = 8; s > 0; s >>= 1) {
        if (sub < s) {
            double ov = rvals[t + 16 * s]; int oi = ridx[t + 16 * s];
            if (ov < rvals[t] || (ov == rvals[t] && oi < ridx[t])) {
                rvals[t] = ov; ridx[t] = oi;
            }
        }
        __syncthreads();
    }
    if (v < nv) {
        const int n = rn[v];
        const int b = n >> 12, hw = n & 4095;
        const int kb = ridx[v];
        #pragma unroll
        for (int j = 0; j < 4; ++j) {
            int d = sub * 4 + j;
            out[(size_t)b * DHW + (size_t)d * HW + hw] = cb[kb * DIM + d];
        }
        if (sub == 0) atomicAdd(loss_acc, rvals[v]);
    }
}

__global__ void vq_finalize(const double* __restrict__ loss_acc,
                            float* __restrict__ loss_out) {
    *loss_out = (float)(1.25 * (*loss_acc) * (1.0 / (double)((long)N_VEC * DIM)));
}

extern "C" void kernel_launch(void* const* d_in, const int* in_sizes, int n_in,
                              void* d_out, int out_size, void* d_ws, size_t ws_size,
                              hipStream_t stream) {
    const float* z  = (const float*)d_in[0];
    const float* cb = (const float*)d_in[1];
    float* out      = (float*)d_out;
    char*  ws       = (char*)d_ws;

    double* loss_acc = (double*)ws;
    int*    counter  = (int*)(ws + 8);
    float*  norms    = (float*)(ws + 64);
    short*  ehg      = (short*)(ws + 8192);
    short*  elg      = (short*)(ws + 139264);
    int*    worklist = (int*)(ws + 270336);

    int cap = WLCAP;
    long avail = ((long)ws_size - 270336) / 4;
    if (avail < cap) cap = (avail > 0) ? (int)avail : 0;

    hipMemsetAsync(d_ws, 0, 16, stream);
    vq_prep<<<dim3(KCODE / 16), dim3(256), 0, stream>>>(cb, norms, ehg, elg);
    vq_main<<<dim3(N_VEC / BLK_ROWS), dim3(256), 0, stream>>>(
        z, cb, norms, ehg, elg, out, loss_acc, counter, worklist, cap);
    vq_rescue<<<dim3(WLCAP / RV), dim3(256), 0, stream>>>(
        z, cb, out, loss_acc, counter, worklist, cap);
    vq_finalize<<<dim3(1), dim3(1), 0, stream>>>(loss_acc, out + (out_size - 1));
}